// Round 1
// baseline (155.586 us; speedup 1.0000x reference)
//
#include <hip/hip_runtime.h>

// qpNet: h = x @ W^T + b ; z = max(-h, -1000). x:[B,5] f32, W:[5,5], b:[5].
// B = 4194304. Memory-bound: 168 MB app traffic, floor ~27 us @ 6.3 TB/s.
//
// R2: 80 B lane stride                -> 57 us (64 lines/instr, 16 B used each)
// R3: LDS transpose + __syncthreads   -> 50 us (barrier vmcnt(0) drain per tile)
// R5: 64 B lane stride + nontemporal  -> 82 us (WRITE_SIZE 1.76x: nt defeats
//     L2 write-combining of partial-line stores)
// R6: wave-private LDS transpose, one-shot waves -> ~48-50 us kernel
//     (hidden below the 49.6-49.9 us harness poison fills in rocprof top-5).
// R7 (this): PERSISTENT WAVES + REGISTER PREFETCH PIPELINE.
//     Diagnosis: R6 waves are one-shot -- 5 loads issued once, then the wave
//     spends ~60% of its life in LDS/compute/store with ZERO reads in flight;
//     blocks launch in phase, so the CU's read pipe oscillates full/empty and
//     refills only at block-retirement granularity. Effective BW ~3.5 TB/s.
//     Fix: each wave owns 4 consecutive tiles; tile t+1's 5 global f4 loads
//     are issued into registers BEFORE tile t's LDS/compute/store phase, so
//     reads stay outstanding continuously. vmcnt never drains to 0 in the
//     loop (compiler emits vmcnt(5) at the next stage-in; the 5 output
//     stores ride along). LDS stays 5 KB/wave (prefetch is in VGPRs), so
//     occupancy is unchanged; grid = 1024 blocks = fully resident.

#define BLOCK 256
#define WAVES_PER_BLOCK 4          // BLOCK / 64
#define F4_PER_TILE 320            // 64 lanes * 5 f4 = 1280 floats = 256 rows
#define TILES_PER_WAVE 4           // 20 KB contiguous per wave

typedef float vf4 __attribute__((ext_vector_type(4)));

__global__ __launch_bounds__(BLOCK) void qpnet_kernel(
    const float* __restrict__ x,
    const float* __restrict__ W,
    const float* __restrict__ bfc,
    float* __restrict__ out,
    int total_f4)
{
    __shared__ __align__(16) float lds[BLOCK * 20];   // 20 KB: 5 KB per wave

    // 5x5 weights + bias in registers (wave-uniform, scalar-cached).
    float w[5][5];
    float bias[5];
#pragma unroll
    for (int j = 0; j < 5; ++j) {
        bias[j] = bfc[j];
#pragma unroll
        for (int i = 0; i < 5; ++i) w[j][i] = W[j * 5 + i];
    }

    const int wave = threadIdx.x >> 6;
    const int lane = threadIdx.x & 63;
    float* __restrict__ wlds = &lds[wave * (64 * 20)];   // this wave's 1280 floats

    const int wave_id = blockIdx.x * WAVES_PER_BLOCK + wave;
    int tb = wave_id * (F4_PER_TILE * TILES_PER_WAVE);   // f4 units; fits int
    if (tb >= total_f4) return;                          // exact division in harness

    const vf4* __restrict__ xin  = reinterpret_cast<const vf4*>(x);
    vf4* __restrict__       zout = reinterpret_cast<vf4*>(out);

    // ---- prologue: tile 0 loads into registers (lane-contiguous, full-line)
    vf4 r[5];
#pragma unroll
    for (int k = 0; k < 5; ++k) r[k] = xin[tb + k * 64 + lane];

    for (int t = 0; t < TILES_PER_WAVE; ++t) {
        const int cur = tb + t * F4_PER_TILE;
        if (cur >= total_f4) break;

        // ---- stage current tile: regs -> LDS (stride-4-word, conflict-free).
        // Compiler inserts s_waitcnt vmcnt(5) here (waits the 5 loads, lets
        // the previous tile's 5 stores stay outstanding).
#pragma unroll
        for (int k = 0; k < 5; ++k)
            *reinterpret_cast<vf4*>(&wlds[(k * 64 + lane) * 4]) = r[k];

        // ---- issue NEXT tile's loads now: in flight across the whole
        // LDS/compute/store phase below. This is the pipeline.
        const int nxt = cur + F4_PER_TILE;
        if (t + 1 < TILES_PER_WAVE && nxt < total_f4) {
#pragma unroll
            for (int k = 0; k < 5; ++k) r[k] = xin[nxt + k * 64 + lane];
        }

        // Intra-wave exchange: SIMD lockstep + in-order DS completion make it
        // correct without __syncthreads; drain lgkm and fence the compiler.
        asm volatile("s_waitcnt lgkmcnt(0)" ::: "memory");

        // ---- transposed read: own 20 consecutive floats = 4 complete rows
        // (word addr lane*20 + 4p: stride-20 f4 groups cover all 32 banks per 8 lanes)
        float v[20];
#pragma unroll
        for (int p = 0; p < 5; ++p)
            *reinterpret_cast<vf4*>(&v[4 * p]) =
                *reinterpret_cast<const vf4*>(&wlds[lane * 20 + 4 * p]);

        // ---- compute: 4 rows x (5x5 matvec + bias + clamp), in place
#pragma unroll
        for (int k = 0; k < 4; ++k) {
            float t0 = bias[0], t1 = bias[1], t2 = bias[2], t3 = bias[3], t4 = bias[4];
#pragma unroll
            for (int i = 0; i < 5; ++i) {
                const float xv = v[k * 5 + i];
                t0 = fmaf(xv, w[0][i], t0);
                t1 = fmaf(xv, w[1][i], t1);
                t2 = fmaf(xv, w[2][i], t2);
                t3 = fmaf(xv, w[3][i], t3);
                t4 = fmaf(xv, w[4][i], t4);
            }
            v[k * 5 + 0] = fmaxf(-t0, -1000.0f);
            v[k * 5 + 1] = fmaxf(-t1, -1000.0f);
            v[k * 5 + 2] = fmaxf(-t2, -1000.0f);
            v[k * 5 + 3] = fmaxf(-t3, -1000.0f);
            v[k * 5 + 4] = fmaxf(-t4, -1000.0f);
        }

        // ---- transposed write back to own region
#pragma unroll
        for (int p = 0; p < 5; ++p)
            *reinterpret_cast<vf4*>(&wlds[lane * 20 + 4 * p]) =
                *reinterpret_cast<const vf4*>(&v[4 * p]);
        asm volatile("s_waitcnt lgkmcnt(0)" ::: "memory");

        // ---- stage out: LDS -> 5 lane-contiguous global f4 stores.
        // Stores overlap the next iteration's stage-in/loads (async, counted
        // but not waited). WAR on LDS vs next iteration's ds_write is safe:
        // the store data is already in VGPRs before any next-iter ds_write
        // issues (data dependency), and same-address DS ops complete in order.
#pragma unroll
        for (int k = 0; k < 5; ++k)
            zout[cur + k * 64 + lane] =
                *reinterpret_cast<const vf4*>(&wlds[(k * 64 + lane) * 4]);
    }
}

extern "C" void kernel_launch(void* const* d_in, const int* in_sizes, int n_in,
                              void* d_out, int out_size, void* d_ws, size_t ws_size,
                              hipStream_t stream) {
    const float* x   = (const float*)d_in[0];   // [B,5]
    const float* W   = (const float*)d_in[1];   // [5,5]
    const float* bfc = (const float*)d_in[2];   // [5]
    float* out = (float*)d_out;                 // [B,5]

    int total_f4 = in_sizes[0] / 4;             // 5,242,880
    int f4_per_wave = F4_PER_TILE * TILES_PER_WAVE;                    // 1280
    int n_waves  = (total_f4 + f4_per_wave - 1) / f4_per_wave;         // 4096
    int grid     = (n_waves + WAVES_PER_BLOCK - 1) / WAVES_PER_BLOCK;  // 1024

    qpnet_kernel<<<grid, BLOCK, 0, stream>>>(x, W, bfc, out, total_f4);
}